// Round 9
// baseline (158.903 us; speedup 1.0000x reference)
//
#include <hip/hip_runtime.h>
#include <math.h>

#define B_ 2
#define N1_ 2048
#define N2_ 512
#define CS_ 384
#define H_ 12
#define PQ_ 8
#define PV_ 12
#define PKV_ 20
#define CQ_ (H_*PQ_*3)    // 288
#define CKV_ (H_*PKV_*3)  // 720
#define INF_ 100000.0f
#define HW_SCALE_ 0.09622504486493764f   // sqrt(1/108)

typedef __attribute__((ext_vector_type(8))) short bf16x8;
typedef __attribute__((ext_vector_type(4))) float f32x4;

__device__ inline unsigned short f2bf(float x) {
  unsigned u = __float_as_uint(x);
  u += 0x7fffu + ((u >> 16) & 1u);      // RNE
  return (unsigned short)(u >> 16);
}

// convert 8 consecutive f32 -> bf16x8 fragment (two dwordx4 loads)
__device__ inline bf16x8 cvt8(const float* __restrict__ p) {
  float4 a = *(const float4*)p;
  float4 b = *(const float4*)(p + 4);
  bf16x8 r;
  r[0] = (short)f2bf(a.x); r[1] = (short)f2bf(a.y);
  r[2] = (short)f2bf(a.z); r[3] = (short)f2bf(a.w);
  r[4] = (short)f2bf(b.x); r[5] = (short)f2bf(b.y);
  r[6] = (short)f2bf(b.z); r[7] = (short)f2bf(b.w);
  return r;
}

// ---------------- prep: LDS-tiled weight transposes + vtb pad + kn zero ----------------
#define TQ_   108   // Wq  384x288: 12 k-tiles x 9 n-tiles
#define TKV_  276   // Wkv 384x720: 12 x 23 (guard n<720)
#define TWO_  216   // Wout 576x384: 18 x 12
#define VPAD_ 72    // vtb comps 36..47 = 0 (147456 elts, 8/thr)
#define KN_   12    // kn = 0 (12288 f32, 4/thr)
__global__ __launch_bounds__(256) void prep_kernel(
    const float* __restrict__ Wq, const float* __restrict__ Wkv,
    const float* __restrict__ Wout,
    unsigned short* __restrict__ wqT, unsigned short* __restrict__ wkvT,
    unsigned short* __restrict__ woutT,
    unsigned short* __restrict__ vtb, float* __restrict__ kn)
{
  __shared__ float lds[32][33];
  int blk = blockIdx.x, t = threadIdx.x;
  int rr0 = t >> 5, cc = t & 31;

  const float* src = nullptr; unsigned short* dst = nullptr;
  int K = 0, N = 0, k0 = 0, n0 = 0;
  if (blk < TQ_) {
    src = Wq; dst = wqT; K = 384; N = CQ_;
    k0 = (blk % 12) * 32; n0 = (blk / 12) * 32;
  } else if (blk < TQ_ + TKV_) {
    int b2 = blk - TQ_;
    src = Wkv; dst = wkvT; K = 384; N = CKV_;
    k0 = (b2 % 12) * 32; n0 = (b2 / 12) * 32;
  } else if (blk < TQ_ + TKV_ + TWO_) {
    int b3 = blk - TQ_ - TKV_;
    src = Wout; dst = woutT; K = 576; N = CS_;
    k0 = (b3 % 18) * 32; n0 = (b3 / 18) * 32;
  } else if (blk < TQ_ + TKV_ + TWO_ + VPAD_) {
    int idx = (blk - TQ_ - TKV_ - TWO_)*256 + t;
    int f = idx * 8;
    int run = f >> 9, off = f & 511;
    int bh = run / 12, cc2 = 36 + run % 12;
    uint4 z = {0u,0u,0u,0u};
    *(uint4*)(vtb + ((size_t)bh*48 + cc2)*512 + off) = z;
    return;
  } else {
    int idx = (blk - TQ_ - TKV_ - TWO_ - VPAD_)*256 + t;
    float4 z = {0.f,0.f,0.f,0.f};
    *(float4*)(kn + (size_t)idx*4) = z;
    return;
  }

  #pragma unroll
  for (int rr = 0; rr < 4; ++rr) {
    int r = rr0 + rr*8;
    if (n0 + cc < N) lds[r][cc] = src[(size_t)(k0 + r)*N + n0 + cc];
  }
  __syncthreads();
  #pragma unroll
  for (int rr = 0; rr < 4; ++rr) {
    int r = rr0 + rr*8;
    if (n0 + r < N) dst[(size_t)(n0 + r)*K + k0 + cc] = f2bf(lds[cc][r]);
  }
}

// ---------------- fused Q + KV projection via MFMA, 2-way k-split ----------------
// 512 thr = 8 waves = 4 units x 2 k-halves. blocks [0,384): q; [384,624): kv.
// kh=1 writes f32 partials to LDS; kh=0 merges, rotates, scatters.
__global__ __launch_bounds__(512) void proj_mfma(
    const float* __restrict__ s1, const float* __restrict__ s2,
    const unsigned short* __restrict__ wqT, const unsigned short* __restrict__ wkvT,
    const float* __restrict__ r1_rot, const float* __restrict__ r1_trans,
    const float* __restrict__ r2_rot, const float* __restrict__ r2_trans,
    unsigned short* __restrict__ qgb, float* __restrict__ qn,
    unsigned short* __restrict__ kgb, unsigned short* __restrict__ vtb,
    float* __restrict__ kn)
{
  __shared__ float acc_s[4][16][48];   // 12288 B
  int wave = threadIdx.x >> 6, lane = threadIdx.x & 63;
  int col = lane & 15, g = lane >> 4;
  int u = wave >> 1, kh = wave & 1;
  int koff = kh * 192;

  if (blockIdx.x < 384) {
    // ---- Q projection ----
    int wg = blockIdx.x*4 + u;           // 0..1535
    int strip = wg / 6;                  // 0..255
    int nt = wg % 6;
    int i0 = strip * 16;

    f32x4 ax = {0.f,0.f,0.f,0.f}, ay = ax, az = ax;
    const float* arow = s1 + (size_t)(i0 + col)*CS_ + koff;
    const unsigned short* bx = wqT + (size_t)((nt     )*16 + col)*CS_ + koff;
    const unsigned short* by = wqT + (size_t)((nt +  6)*16 + col)*CS_ + koff;
    const unsigned short* bz = wqT + (size_t)((nt + 12)*16 + col)*CS_ + koff;
    #pragma unroll
    for (int k = 0; k < 192; k += 32) {
      bf16x8 a = cvt8(arow + k + g*8);
      ax = __builtin_amdgcn_mfma_f32_16x16x32_bf16(a, *(const bf16x8*)(bx + k + g*8), ax, 0,0,0);
      ay = __builtin_amdgcn_mfma_f32_16x16x32_bf16(a, *(const bf16x8*)(by + k + g*8), ay, 0,0,0);
      az = __builtin_amdgcn_mfma_f32_16x16x32_bf16(a, *(const bf16x8*)(bz + k + g*8), az, 0,0,0);
    }
    if (kh) {
      #pragma unroll
      for (int r = 0; r < 4; ++r) {
        acc_s[u][g*4 + r][col]      = ax[r];
        acc_s[u][g*4 + r][16 + col] = ay[r];
        acc_s[u][g*4 + r][32 + col] = az[r];
      }
    }
    __syncthreads();
    if (kh) return;
    #pragma unroll
    for (int r = 0; r < 4; ++r) {
      ax[r] += acc_s[u][g*4 + r][col];
      ay[r] += acc_s[u][g*4 + r][16 + col];
      az[r] += acc_s[u][g*4 + r][32 + col];
    }

    int p = nt*16 + col;
    int h = p >> 3, pq = p & 7;
    float qsum[4];
    #pragma unroll
    for (int r = 0; r < 4; ++r) {
      int row = i0 + g*4 + r;
      const float* R  = r1_rot   + (size_t)row*9;
      const float* tr = r1_trans + (size_t)row*3;
      float x = ax[r], y = ay[r], z = az[r];
      float g0 = R[0]*x + R[1]*y + R[2]*z + tr[0];
      float g1 = R[3]*x + R[4]*y + R[5]*z + tr[1];
      float g2 = R[6]*x + R[7]*y + R[8]*z + tr[2];
      int b = row >> 11, i = row & (N1_-1);
      size_t rbase = ((size_t)(b*H_ + h)*N1_ + i)*32;
      qgb[rbase + pq*3]     = f2bf(g0);
      qgb[rbase + pq*3 + 1] = f2bf(g1);
      qgb[rbase + pq*3 + 2] = f2bf(g2);
      if (pq == 7) {
        uint4 z4 = {0u,0u,0u,0u};
        *(uint4*)(qgb + rbase + 24) = z4;
      }
      qsum[r] = g0*g0 + g1*g1 + g2*g2;
    }
    #pragma unroll
    for (int r = 0; r < 4; ++r) {
      qsum[r] += __shfl_xor(qsum[r], 1);
      qsum[r] += __shfl_xor(qsum[r], 2);
      qsum[r] += __shfl_xor(qsum[r], 4);
    }
    if ((col & 7) == 0) {
      int hh = nt*2 + (col >> 3);
      #pragma unroll
      for (int r = 0; r < 4; ++r) {
        int row = i0 + g*4 + r;
        int b = row >> 11, i = row & (N1_-1);
        qn[(size_t)(b*H_ + hh)*N1_ + i] = qsum[r];
      }
    }
  } else {
    // ---- KV projection ----
    int wg = (blockIdx.x - 384)*4 + u;     // 0..959
    int strip = wg / 15;                   // 0..63
    int nt = wg % 15;                      // 0..14
    int row0 = strip * 16;

    f32x4 ax = {0.f,0.f,0.f,0.f}, ay = ax, az = ax;
    const float* arow = s2 + (size_t)(row0 + col)*CS_ + koff;
    const unsigned short* bx = wkvT + (size_t)(nt*16       + col)*CS_ + koff;
    const unsigned short* by = wkvT + (size_t)(nt*16 + 240 + col)*CS_ + koff;
    const unsigned short* bz = wkvT + (size_t)(nt*16 + 480 + col)*CS_ + koff;
    #pragma unroll
    for (int k = 0; k < 192; k += 32) {
      bf16x8 a = cvt8(arow + k + g*8);
      ax = __builtin_amdgcn_mfma_f32_16x16x32_bf16(a, *(const bf16x8*)(bx + k + g*8), ax, 0,0,0);
      ay = __builtin_amdgcn_mfma_f32_16x16x32_bf16(a, *(const bf16x8*)(by + k + g*8), ay, 0,0,0);
      az = __builtin_amdgcn_mfma_f32_16x16x32_bf16(a, *(const bf16x8*)(bz + k + g*8), az, 0,0,0);
    }
    if (kh) {
      #pragma unroll
      for (int r = 0; r < 4; ++r) {
        acc_s[u][g*4 + r][col]      = ax[r];
        acc_s[u][g*4 + r][16 + col] = ay[r];
        acc_s[u][g*4 + r][32 + col] = az[r];
      }
    }
    __syncthreads();
    if (kh) return;
    #pragma unroll
    for (int r = 0; r < 4; ++r) {
      ax[r] += acc_s[u][g*4 + r][col];
      ay[r] += acc_s[u][g*4 + r][16 + col];
      az[r] += acc_s[u][g*4 + r][32 + col];
    }

    int p = nt*16 + col;
    int h = p / PKV_, pp = p % PKV_;
    #pragma unroll
    for (int r = 0; r < 4; ++r) {
      int row = row0 + g*4 + r;
      const float* R  = r2_rot   + (size_t)row*9;
      const float* tr = r2_trans + (size_t)row*3;
      float x = ax[r], y = ay[r], z = az[r];
      float g0 = R[0]*x + R[1]*y + R[2]*z + tr[0];
      float g1 = R[3]*x + R[4]*y + R[5]*z + tr[1];
      float g2 = R[6]*x + R[7]*y + R[8]*z + tr[2];
      int b = row >> 9, j = row & (N2_-1);
      int bh = b*H_ + h;
      if (pp < PQ_) {
        size_t base = ((size_t)bh*N2_ + j)*32 + pp*3;
        kgb[base]   = f2bf(g0);
        kgb[base+1] = f2bf(g1);
        kgb[base+2] = f2bf(g2);
        if (pp == 0) {
          uint4 z4 = {0u,0u,0u,0u};
          *(uint4*)(kgb + ((size_t)bh*N2_ + j)*32 + 24) = z4;
        }
        atomicAdd(&kn[(size_t)bh*N2_ + j], g0*g0 + g1*g1 + g2*g2);
      } else {
        int comp = (pp - PQ_)*3;
        size_t base = ((size_t)bh*48 + comp)*512 + j;
        vtb[base]        = f2bf(g0);
        vtb[base + 512]  = f2bf(g1);
        vtb[base + 1024] = f2bf(g2);
      }
    }
  }
}

// ---------------- MFMA flash attention, 4-way j-split ----------------
// block = one 16-i tile, 4 waves; wave w handles jt in {2w, 2w+1} (128 j).
// Linear partials (o,l) -> LDS slots; single barrier; wave 0 merges 4 slots
// and runs the epilogue.
#define RSTRIDE 72
#define OSTRIDE 52
__global__ __launch_bounds__(256) void attn_kernel(
    const unsigned short* __restrict__ qgb, const float* __restrict__ qn,
    const unsigned short* __restrict__ kgb, const unsigned short* __restrict__ vtb,
    const float* __restrict__ kn, const float* __restrict__ mask1,
    const float* __restrict__ mask2, const float* __restrict__ hwts,
    const float* __restrict__ rot, const float* __restrict__ trans,
    unsigned short* __restrict__ featsb)
{
  __shared__ __align__(16) unsigned short pstrip[4][16][RSTRIDE];
  __shared__ float o_s[4][16][OSTRIDE];
  __shared__ float l_s[4][16];

  int wave = threadIdx.x >> 6;
  int lane = threadIdx.x & 63;
  int col = lane & 15, g = lane >> 4;
  int mt = blockIdx.x;                 // i-tile id 0..3071
  int bh = mt >> 7;
  int it = mt & 127;
  int b = bh / H_, h = bh - b*H_;

  float hw = logf(1.0f + __expf(hwts[h])) * HW_SCALE_;

  bf16x8 qa = *(const bf16x8*)(qgb + (((size_t)bh*N1_ + it*16 + col)*32 + g*8));

  float ar[4], m1r[4];
  #pragma unroll
  for (int r = 0; r < 4; ++r) {
    int ig = it*16 + g*4 + r;
    ar[r]  = fmaf(-0.5f*hw, qn[(size_t)bh*N1_ + ig], -INF_);
    m1r[r] = mask1[b*N1_ + ig] * INF_;
  }

  f32x4 ot[3];
  #pragma unroll
  for (int m = 0; m < 3; ++m) ot[m] = (f32x4){0.f,0.f,0.f,0.f};
  float l[4] = {0.f,0.f,0.f,0.f};

  const unsigned short* kbase = kgb + (size_t)bh*N2_*32;
  const unsigned short* vbase = vtb + (size_t)bh*48*512;
  const float* knp = kn + (size_t)bh*N2_;
  const float* m2p = mask2 + b*N2_;

  #pragma unroll
  for (int jj = 0; jj < 2; ++jj) {
    int jt = wave*2 + jj;
    int j0 = jt*64;
    #pragma unroll
    for (int nt = 0; nt < 4; ++nt) {
      int jg = j0 + nt*16 + col;
      bf16x8 kb = *(const bf16x8*)(kbase + ((size_t)jg*32 + g*8));
      f32x4 dotv = __builtin_amdgcn_mfma_f32_16x16x32_bf16(
          qa, kb, (f32x4){0.f,0.f,0.f,0.f}, 0, 0, 0);
      float bc  = -0.5f*hw*knp[jg];
      float m2c = m2p[jg];
      #pragma unroll
      for (int r = 0; r < 4; ++r) {
        float logit = fmaf(hw, dotv[r], fmaf(m1r[r], m2c, ar[r] + bc));
        float w = __expf(logit);
        l[r] += w;
        pstrip[wave][g*4 + r][nt*16 + col] = f2bf(w);
      }
    }
    #pragma unroll
    for (int ks = 0; ks < 2; ++ks) {
      bf16x8 pb = *(const bf16x8*)&pstrip[wave][col][ks*32 + g*8];
      #pragma unroll
      for (int mtv = 0; mtv < 3; ++mtv) {
        bf16x8 va = *(const bf16x8*)(vbase +
            ((size_t)(mtv*16 + col))*512 + j0 + ks*32 + g*8);
        ot[mtv] = __builtin_amdgcn_mfma_f32_16x16x32_bf16(va, pb, ot[mtv], 0, 0, 0);
      }
    }
  }

  // stash partials: l reduced over the 16 cols first
  #pragma unroll
  for (int r = 0; r < 4; ++r) {
    l[r] += __shfl_xor(l[r], 1);
    l[r] += __shfl_xor(l[r], 2);
    l[r] += __shfl_xor(l[r], 4);
    l[r] += __shfl_xor(l[r], 8);
  }
  if (col == 0) {
    #pragma unroll
    for (int r = 0; r < 4; ++r) l_s[wave][g*4 + r] = l[r];
  }
  #pragma unroll
  for (int mtv = 0; mtv < 3; ++mtv)
    #pragma unroll
    for (int r = 0; r < 4; ++r)
      o_s[wave][col][mtv*16 + g*4 + r] = ot[mtv][r];
  __syncthreads();
  if (wave != 0) return;

  // wave 0: merge 4 slots + epilogue
  float inv = 1.0f / (l_s[0][col] + l_s[1][col] + l_s[2][col] + l_s[3][col]);
  int ig = it*16 + col;
  int row = b*N1_ + ig;
  const float* R  = rot   + (size_t)row*9;
  const float* tr = trans + (size_t)row*3;
  float R00=R[0],R01=R[1],R02=R[2],R10=R[3],R11=R[4],R12=R[5],R20=R[6],R21=R[7],R22=R[8];
  float t0=tr[0], t1=tr[1], t2=tr[2];
  unsigned short* fb = featsb + (size_t)row*576 + h*PV_;
  #pragma unroll
  for (int p = 0; p < 3; ++p) {
    int pt = g*3 + p;
    float ox = (o_s[0][col][pt*3+0] + o_s[1][col][pt*3+0] +
                o_s[2][col][pt*3+0] + o_s[3][col][pt*3+0])*inv - t0;
    float oy = (o_s[0][col][pt*3+1] + o_s[1][col][pt*3+1] +
                o_s[2][col][pt*3+1] + o_s[3][col][pt*3+1])*inv - t1;
    float oz = (o_s[0][col][pt*3+2] + o_s[1][col][pt*3+2] +
                o_s[2][col][pt*3+2] + o_s[3][col][pt*3+2])*inv - t2;
    float lx = R00*ox + R10*oy + R20*oz;
    float ly = R01*ox + R11*oy + R21*oz;
    float lz = R02*ox + R12*oy + R22*oz;
    float dist = sqrtf(lx*lx + ly*ly + lz*lz + 1e-8f);
    fb[pt]       = f2bf(lx);
    fb[144 + pt] = f2bf(ly);
    fb[288 + pt] = f2bf(lz);
    fb[432 + pt] = f2bf(dist);
  }
}

// ---------------- Output projection via MFMA, 2-way k-split ----------------
__global__ __launch_bounds__(1024) void outproj_mfma(
    const unsigned short* __restrict__ featsb, const unsigned short* __restrict__ woutT,
    const float* __restrict__ bout, float* __restrict__ out)
{
  __shared__ float acc_s[8][16][48];   // 24576 B
  int wave = threadIdx.x >> 6, lane = threadIdx.x & 63;
  int col = lane & 15, g = lane >> 4;
  int nw = wave & 7, kh = wave >> 3;
  int i0 = blockIdx.x * 16;
  int n0 = nw * 48;

  f32x4 acc[3];
  #pragma unroll
  for (int m = 0; m < 3; ++m) acc[m] = (f32x4){0.f,0.f,0.f,0.f};
  const unsigned short* arow = featsb + (size_t)(i0 + col)*576 + kh*288;
  const unsigned short* b0 = woutT + (size_t)(n0      + col)*576 + kh*288;
  const unsigned short* b1 = woutT + (size_t)(n0 + 16 + col)*576 + kh*288;
  const unsigned short* b2 = woutT + (size_t)(n0 + 32 + col)*576 + kh*288;
  #pragma unroll 3
  for (int k = 0; k < 288; k += 32) {
    bf16x8 a = *(const bf16x8*)(arow + k + g*8);
    acc[0] = __builtin_amdgcn_mfma_f32_16x16x32_bf16(a, *(const bf16x8*)(b0 + k + g*8), acc[0], 0,0,0);
    acc[1] = __builtin_amdgcn_mfma_f32_16x16x32_bf16(a, *(const bf16x8*)(b1 + k + g*8), acc[1], 0,0,0);
    acc[2] = __builtin_amdgcn_mfma_f32_16x16x32_bf16(a, *(const bf16x8*)(b2 + k + g*8), acc[2], 0,0,0);
  }
  if (kh) {
    #pragma unroll
    for (int t3 = 0; t3 < 3; ++t3)
      #pragma unroll
      for (int r = 0; r < 4; ++r)
        acc_s[nw][g*4 + r][t3*16 + col] = acc[t3][r];
  }
  __syncthreads();
  if (kh) return;
  #pragma unroll
  for (int t3 = 0; t3 < 3; ++t3) {
    int n = n0 + t3*16 + col;
    float bb = bout[n];
    #pragma unroll
    for (int r = 0; r < 4; ++r) {
      int row = i0 + g*4 + r;
      out[(size_t)row*CS_ + n] = acc[t3][r] + acc_s[nw][g*4 + r][t3*16 + col] + bb;
    }
  }
}

extern "C" void kernel_launch(void* const* d_in, const int* in_sizes, int n_in,
                              void* d_out, int out_size, void* d_ws, size_t ws_size,
                              hipStream_t stream) {
  const float* s1       = (const float*)d_in[0];
  const float* s2       = (const float*)d_in[1];
  const float* r1_rot   = (const float*)d_in[2];
  const float* r1_trans = (const float*)d_in[3];
  const float* r2_rot   = (const float*)d_in[4];
  const float* r2_trans = (const float*)d_in[5];
  const float* mask1    = (const float*)d_in[6];
  const float* mask2    = (const float*)d_in[7];
  const float* Wq       = (const float*)d_in[8];
  const float* Wkv      = (const float*)d_in[9];
  const float* hwts     = (const float*)d_in[10];
  const float* Wout     = (const float*)d_in[11];
  const float* bout     = (const float*)d_in[12];
  float* out = (float*)d_out;

  float* qn = (float*)d_ws;                              // 49152 f32
  float* kn = qn + (size_t)B_*H_*N1_;                    // 12288 f32
  unsigned short* featsb = (unsigned short*)(kn + (size_t)B_*H_*N2_); // 2359296 u16
  unsigned short* qgb  = featsb + (size_t)B_*N1_*576;    // 1572864 u16
  unsigned short* kgb  = qgb  + (size_t)B_*H_*N1_*32;    // 393216 u16
  unsigned short* vtb  = kgb  + (size_t)B_*H_*N2_*32;    // 589824 u16
  unsigned short* wqT  = vtb  + (size_t)B_*H_*48*512;    // 110592 u16
  unsigned short* wkvT = wqT  + (size_t)CQ_*CS_;         // 276480 u16
  unsigned short* woutT= wkvT + (size_t)CKV_*CS_;        // 221184 u16

  prep_kernel<<<TQ_+TKV_+TWO_+VPAD_+KN_, 256, 0, stream>>>(
      Wq, Wkv, Wout, wqT, wkvT, woutT, vtb, kn);
  proj_mfma<<<624, 512, 0, stream>>>(s1, s2, wqT, wkvT, r1_rot, r1_trans,
                                     r2_rot, r2_trans, qgb, qn, kgb, vtb, kn);
  attn_kernel<<<B_*H_*(N1_/16), 256, 0, stream>>>(qgb, qn, kgb, vtb, kn, mask1, mask2,
                                                  hwts, r1_rot, r1_trans, featsb);
  outproj_mfma<<<256, 1024, 0, stream>>>(featsb, woutT, bout, out);
}